// Round 2
// 279.541 us; speedup vs baseline: 1.0170x; 1.0170x over previous
//
#include <hip/hip_runtime.h>

typedef __attribute__((ext_vector_type(8))) short short8;
typedef __attribute__((ext_vector_type(4))) float floatx4;
typedef __attribute__((ext_vector_type(4))) int   intx4;

#define NEG_SLOPE 0.01f

__device__ __forceinline__ short f2bf(float f) {
    // round-to-nearest-even fp32 -> bf16
    unsigned u = __float_as_uint(f);
    unsigned r = (u + 0x7FFFu + ((u >> 16) & 1u)) >> 16;
    return (short)r;
}

__device__ __forceinline__ int pack2(float x, float y) {
    return (int)(unsigned short)f2bf(x) | ((int)(unsigned short)f2bf(y) << 16);
}

// One block handles (b, iBase..iBase+7); one wave per i. 8 waves/block,
// 2 blocks/CU -> 16 waves/CU (was 8) to hide VALU/shfl/exp latency chains
// and keep the store queue fed.
// qk[j,e] = sum_d E[j][d] * (W[e][d]*ei[d])  via mfma_f32_16x16x32_bf16:
//   A-operand = E rows (M=j), B-operand = (W o ei) rows (N=e), K=d.
__global__ __launch_bounds__(512, 4)
void afm_kernel(const float* __restrict__ emb,
                const float* __restrict__ wW,
                const float* __restrict__ wb,
                const float* __restrict__ aW,
                float* __restrict__ aOut,
                float* __restrict__ vOut) {
    __shared__ __align__(16) float sEf[64][68];   // E_b fp32, padded (+4) -> conflict-free
    __shared__ __align__(16) float sW [64][68];   // W fp32, padded
    __shared__ __align__(16) short sEb[64][72];   // E_b bf16, padded (+8 shorts = 16B)
    __shared__ __align__(16) float sei[8][64];    // per-wave e_i fp32
    __shared__ __align__(16) float swb[64];
    __shared__ __align__(16) float saw[64];
    __shared__ __align__(16) float slog[8][64];

    const int tid   = threadIdx.x;
    const int lane  = tid & 63;
    const int w     = tid >> 6;          // wave id 0..7
    const int blk   = blockIdx.x;        // 0..2047
    const int b     = blk >> 3;          // 0..255
    const int iBase = (blk & 7) << 3;
    const int i     = iBase + w;

    const float* embB = emb + (size_t)b * 4096;

    // ---------------- load / stage phase ----------------
    {
        int row = tid >> 3;              // 0..63
        int c0  = (tid & 7) << 3;        // 0,8,...,56
        const float* src = embB + row * 64 + c0;
        float4 a0 = *(const float4*)(src);
        float4 a1 = *(const float4*)(src + 4);
        *(float4*)&sEf[row][c0]     = a0;
        *(float4*)&sEf[row][c0 + 4] = a1;
        intx4 q;
        q[0] = pack2(a0.x, a0.y); q[1] = pack2(a0.z, a0.w);
        q[2] = pack2(a1.x, a1.y); q[3] = pack2(a1.z, a1.w);
        *(intx4*)&sEb[row][c0] = q;      // row stride 144B, c0*2 multiple of 16 -> aligned

        const float* wsrc = wW + row * 64 + c0;
        float4 b0 = *(const float4*)(wsrc);
        float4 b1 = *(const float4*)(wsrc + 4);
        *(float4*)&sW[row][c0]     = b0;
        *(float4*)&sW[row][c0 + 4] = b1;

        sei[w][lane] = embB[i * 64 + lane];
        if (tid < 64)        swb[tid]       = wb[tid];
        else if (tid < 128)  saw[tid - 64]  = aW[tid - 64];
    }
    __syncthreads();

    // ---------------- value stream phase (fire-and-forget nt stores) ----------------
    {
        float* base = vOut + ((size_t)(b * 64 + i) << 12);
        const int joff = lane >> 4;          // 0..3
        const int d0   = (lane & 15) << 2;   // 0..60
        float4 ei = *(float4*)&sei[w][d0];
        #pragma unroll
        for (int c = 0; c < 16; ++c) {
            int j = (c << 2) + joff;
            float4 ej = *(float4*)&sEf[j][d0];
            floatx4 v;
            v[0] = ei.x * ej.x; v[1] = ei.y * ej.y;
            v[2] = ei.z * ej.z; v[3] = ei.w * ej.w;
            // write-only 268MB stream: bypass L2 (clang native vector type
            // required — HIP float4 is a class and is rejected)
            __builtin_nontemporal_store(v, (floatx4*)(base + (c << 8) + (lane << 2)));
        }
    }

    // ---------------- qk via MFMA ----------------
    const int lo = lane & 15, hi = lane >> 4;

    // Hoist BOTH K-slices' B-fragments (32 VGPR) so acc can be consumed
    // per-jt (16 live VGPR) instead of acc[4][4] (64 VGPR): stays under
    // the 128-VGPR cap that 4 waves/EU imposes.
    short8 bf[2][4];
    #pragma unroll
    for (int kt = 0; kt < 2; ++kt) {
        const int d0 = kt * 32 + hi * 8;
        float4 ei0 = *(float4*)&sei[w][d0];
        float4 ei1 = *(float4*)&sei[w][d0 + 4];
        #pragma unroll
        for (int et = 0; et < 4; ++et) {
            int e = et * 16 + lo;
            float4 w0 = *(float4*)&sW[e][d0];
            float4 w1 = *(float4*)&sW[e][d0 + 4];
            short8 t;
            t[0] = f2bf(w0.x * ei0.x); t[1] = f2bf(w0.y * ei0.y);
            t[2] = f2bf(w0.z * ei0.z); t[3] = f2bf(w0.w * ei0.w);
            t[4] = f2bf(w1.x * ei1.x); t[5] = f2bf(w1.y * ei1.y);
            t[6] = f2bf(w1.z * ei1.z); t[7] = f2bf(w1.w * ei1.w);
            bf[kt][et] = t;
        }
    }

    float wbv[4], awv[4];
    #pragma unroll
    for (int et = 0; et < 4; ++et) {
        int e = et * 16 + lo;
        wbv[et] = swb[e];
        awv[et] = saw[e];
    }

    float lg[16];
    #pragma unroll
    for (int jt = 0; jt < 4; ++jt) {
        floatx4 acc[4];
        #pragma unroll
        for (int et = 0; et < 4; ++et)
            acc[et] = (floatx4){0.f, 0.f, 0.f, 0.f};
        #pragma unroll
        for (int kt = 0; kt < 2; ++kt) {
            short8 af = *(short8*)&sEb[jt * 16 + lo][kt * 32 + hi * 8];
            #pragma unroll
            for (int et = 0; et < 4; ++et)
                acc[et] = __builtin_amdgcn_mfma_f32_16x16x32_bf16(
                    af, bf[kt][et], acc[et], 0, 0, 0);
        }
        // consume acc[jt] immediately: bias + leaky + aW dot + lane-reduce
        #pragma unroll
        for (int r = 0; r < 4; ++r) {
            float p = 0.f;
            #pragma unroll
            for (int et = 0; et < 4; ++et) {
                float x = acc[et][r] + wbv[et];
                x = fmaxf(x, NEG_SLOPE * x);   // leaky (slope<1)
                p += awv[et] * x;
            }
            // reduce over the 16 lanes holding different e-residues
            p += __shfl_xor(p, 1);
            p += __shfl_xor(p, 2);
            p += __shfl_xor(p, 4);
            p += __shfl_xor(p, 8);
            lg[jt * 4 + r] = p;   // logit[j], j = jt*16 + hi*4 + r (a_b dropped: shift-invariant)
        }
    }

    // ---------------- softmax ----------------
    float m = lg[0];
    #pragma unroll
    for (int k = 1; k < 16; ++k) m = fmaxf(m, lg[k]);
    m = fmaxf(m, __shfl_xor(m, 16));
    m = fmaxf(m, __shfl_xor(m, 32));

    float ex[16];
    float s = 0.f;
    #pragma unroll
    for (int k = 0; k < 16; ++k) { ex[k] = __expf(lg[k] - m); s += ex[k]; }
    s += __shfl_xor(s, 16);
    s += __shfl_xor(s, 32);
    float inv = 1.f / s;

    if (lo == 0) {
        #pragma unroll
        for (int jt = 0; jt < 4; ++jt)
            #pragma unroll
            for (int r = 0; r < 4; ++r)
                slog[w][jt * 16 + hi * 4 + r] = ex[jt * 4 + r] * inv;
    }
    __syncthreads();
    aOut[((size_t)(b * 64 + i) << 6) + lane] = slog[w][lane];
}

extern "C" void kernel_launch(void* const* d_in, const int* in_sizes, int n_in,
                              void* d_out, int out_size, void* d_ws, size_t ws_size,
                              hipStream_t stream) {
    const float* emb = (const float*)d_in[0];   // [256,64,64]
    const float* wW  = (const float*)d_in[1];   // [64,64]
    const float* wb  = (const float*)d_in[2];   // [64]
    const float* aW  = (const float*)d_in[3];   // [64]
    // d_in[4] = a_b : softmax is shift-invariant, unused.
    float* aOut = (float*)d_out;                 // [256,64,64,1]
    float* vOut = aOut + (size_t)256 * 64 * 64;  // [256,64,64,64]
    afm_kernel<<<2048, 512, 0, stream>>>(emb, wW, wb, aW, aOut, vOut);
}